// Round 6
// baseline (73.251 us; speedup 1.0000x reference)
//
#include <hip/hip_runtime.h>
#include <hip/hip_bf16.h>

typedef __bf16 bf16x8 __attribute__((ext_vector_type(8)));
typedef __bf16 bf16x4 __attribute__((ext_vector_type(4)));
typedef float  f32x4  __attribute__((ext_vector_type(4)));

#define LDP 72  // padded LDS row stride in bf16 elems (144B)

// Raw barrier: drain DS only (cross-wave LDS visibility). Deliberately NO vmcnt:
// in-flight global prefetch loads survive the barrier (T3/T4; __syncthreads would
// emit s_waitcnt vmcnt(0) and kill the pipeline).
#define BAR() { asm volatile("s_waitcnt lgkmcnt(0)" ::: "memory"); __builtin_amdgcn_s_barrier(); }

// ---------------- Kernel 0: W -> bf16 pre-conversion ----------------
__global__ __launch_bounds__(256) void wconv_kernel(
    const float* __restrict__ Wk, const float* __restrict__ Wq,
    const float* __restrict__ Wv, __bf16* __restrict__ wbf)
{
    int idx = blockIdx.x * 256 + threadIdx.x;      // 0 .. 49151
    int row = idx >> 8;
    int c4  = idx & 255;
    const float* wp = (row < 64) ? Wk + (size_t)row * 1024
                    : (row < 128) ? Wq + (size_t)(row - 64) * 1024
                                  : Wv + (size_t)(row - 128) * 1024;
    float4 f = *reinterpret_cast<const float4*>(wp + c4 * 4);
    bf16x4 v; v[0] = (__bf16)f.x; v[1] = (__bf16)f.y; v[2] = (__bf16)f.z; v[3] = (__bf16)f.w;
    *reinterpret_cast<bf16x4*>(&wbf[(size_t)row * 1024 + c4 * 4]) = v;
}

// ---------------- Kernel 1: fused QKV projection GEMM (true depth-2 pipeline) ----------------
// Loads for K-block j+2 issued at top of iter j; they stay in flight across the raw
// barrier (no vmcnt drain). COMMIT of set j+1 waits only on its own loads (counted vmcnt).
__global__ __launch_bounds__(1024) void proj_kernel(
    const float* __restrict__ x, const __bf16* __restrict__ wbf,
    __bf16* __restrict__ kbuf, __bf16* __restrict__ qbuf, __bf16* __restrict__ vtbuf)
{
    __shared__ __align__(16) __bf16 Slds[2][256 * LDP];
    __shared__ __align__(16) __bf16 Vtl[64 * LDP];

    const int tid  = threadIdx.x;
    const int lane = tid & 63;
    const int wid  = tid >> 6;     // 0..15
    const int wm   = wid >> 2;     // 0..3 : 16-row group
    const int wn   = wid & 3;      // 0..3 : 48-col group
    const int mbase = blockIdx.x * 64;

    const int cl = lane & 15;
    const int e0 = (lane >> 4) * 8;
    const int r0 = (lane >> 4) * 4;

    const int arow = tid >> 4, acg = tid & 15;
    const float* aptr = x + (size_t)(mbase + arow) * 1024 + acg * 4;

    float4 a0, a1;
    bf16x4 w0[3], w1[3];

#define ISSUE(aset, wset, kb) { \
    aset = *reinterpret_cast<const float4*>(aptr + (kb)); \
    _Pragma("unroll") \
    for (int i_ = 0; i_ < 3; i_++) { \
        int c_ = i_ * 1024 + tid; \
        wset[i_] = *reinterpret_cast<const bf16x4*>(&wbf[(size_t)(c_ >> 4) * 1024 + (kb) + (c_ & 15) * 4]); \
    } }

#define COMMIT(aset, wset, bufi) { \
    bf16x4 av_; \
    av_[0] = (__bf16)aset.x; av_[1] = (__bf16)aset.y; av_[2] = (__bf16)aset.z; av_[3] = (__bf16)aset.w; \
    *reinterpret_cast<bf16x4*>(&Slds[bufi][arow * LDP + acg * 4]) = av_; \
    _Pragma("unroll") \
    for (int i_ = 0; i_ < 3; i_++) { \
        int c_ = i_ * 1024 + tid; \
        *reinterpret_cast<bf16x4*>(&Slds[bufi][(64 + (c_ >> 4)) * LDP + (c_ & 15) * 4]) = wset[i_]; \
    } }

    f32x4 acc[3];
    #pragma unroll
    for (int n = 0; n < 3; n++) acc[n] = (f32x4){0.f, 0.f, 0.f, 0.f};

    // prologue: kb0 commit; kb1 in flight across the barrier
    ISSUE(a0, w0, 0);
    COMMIT(a0, w0, 0);
    ISSUE(a1, w1, 64);
    BAR();

    #pragma unroll 2
    for (int j = 0; j < 16; j++) {
        // issue kb j+2 into the set freed by last iteration's commit
        if (j < 14) {
            if (j & 1) { ISSUE(a1, w1, (j + 2) * 64); }
            else       { ISSUE(a0, w0, (j + 2) * 64); }
        }
        const __bf16* buf = Slds[j & 1];
        #pragma unroll
        for (int kk = 0; kk < 2; kk++) {
            bf16x8 a = *reinterpret_cast<const bf16x8*>(&buf[(wm * 16 + cl) * LDP + kk * 32 + e0]);
            #pragma unroll
            for (int nf = 0; nf < 3; nf++) {
                bf16x8 b = *reinterpret_cast<const bf16x8*>(&buf[(64 + wn * 48 + nf * 16 + cl) * LDP + kk * 32 + e0]);
                acc[nf] = __builtin_amdgcn_mfma_f32_16x16x32_bf16(a, b, acc[nf], 0, 0, 0);
            }
        }
        if (j < 15) {
            // commit set for K-block j+1 (its loads are the OLDER outstanding set -> counted vmcnt)
            if (j & 1) { COMMIT(a0, w0, 0); }
            else       { COMMIT(a1, w1, 1); }
            BAR();
        }
    }
#undef ISSUE
#undef COMMIT

    // epilogue: k,q direct bf16 stores; v -> LDS transpose -> vtbuf
    #pragma unroll
    for (int nf = 0; nf < 3; nf++) {
        int c = wn * 48 + nf * 16 + cl;
        #pragma unroll
        for (int r = 0; r < 4; r++) {
            int mrel = wm * 16 + r0 + r;
            float v = acc[nf][r];
            if (c < 64)        kbuf[(size_t)(mbase + mrel) * 64 + c]         = (__bf16)v;
            else if (c < 128)  qbuf[(size_t)(mbase + mrel) * 64 + (c - 64)]  = (__bf16)v;
            else               Vtl[(c - 128) * LDP + mrel]                   = (__bf16)v;
        }
    }
    __syncthreads();
    {
        int b   = mbase >> 11;
        int tof = mbase & 2047;
        int h   = tid >> 4;
        int seg = tid & 15;
        bf16x4 v4 = *reinterpret_cast<const bf16x4*>(&Vtl[h * LDP + seg * 4]);
        *reinterpret_cast<bf16x4*>(&vtbuf[(size_t)b * 64 * 2048 + (size_t)h * 2048 + tof + seg * 4]) = v4;
    }
}

// ---------------- Kernel 2: flash attention, split KV, pipelined staging ----------------
// Next tile's K/V loads are issued BEFORE this tile's compute and stay in flight
// across the raw barrier; one barrier per tile (was 2 __syncthreads drains).
__global__ __launch_bounds__(256) void attn_kernel(
    const __bf16* __restrict__ qbuf, const __bf16* __restrict__ kbuf,
    const __bf16* __restrict__ vtbuf, const int* __restrict__ mask,
    float* __restrict__ out, float* __restrict__ accpart, float* __restrict__ mlpart,
    int nsplit, int tps)
{
    __shared__ __align__(16) __bf16 Klds[2][64 * LDP];
    __shared__ __align__(16) __bf16 Vlds[2][64 * LDP];
    __shared__ __align__(16) __bf16 Plds[4][16 * LDP];

    const int tid  = threadIdx.x;
    const int lane = tid & 63;
    const int w    = tid >> 6;
    const int qt   = blockIdx.x;
    const int sp   = blockIdx.y;
    const int b    = blockIdx.z;
    const int qbase = qt * 64 + w * 16;

    const int jbeg = sp * tps;
    const int jend = min((sp + 1) * tps, qt + 1);

    if (nsplit > 1 && jbeg >= jend) {
        float* ap = accpart + ((size_t)(b * nsplit + sp) * 2048 + qt * 64) * 64;
        for (int i = tid; i < 64 * 64; i += 256) ap[i] = 0.f;
        float* mp = mlpart + ((size_t)(b * nsplit + sp) * 2048 + qt * 64) * 2;
        for (int i = tid; i < 64; i += 256) { mp[2 * i] = -INFINITY; mp[2 * i + 1] = 0.f; }
        return;
    }

    const int cl = lane & 15;
    const int e0 = (lane >> 4) * 8;
    const int r0 = (lane >> 4) * 4;

    bf16x8 aq[2];
    #pragma unroll
    for (int kk = 0; kk < 2; kk++)
        aq[kk] = *reinterpret_cast<const bf16x8*>(&qbuf[((size_t)b * 2048 + qbase + cl) * 64 + kk * 32 + e0]);

    float ms[4], ls[4];
    f32x4 acc[4];
    #pragma unroll
    for (int r = 0; r < 4; r++) { ms[r] = -INFINITY; ls[r] = 0.f; }
    #pragma unroll
    for (int hf = 0; hf < 4; hf++) acc[hf] = (f32x4){0.f, 0.f, 0.f, 0.f};

    const int srow = tid >> 3;   // 0..31
    const int scg  = tid & 7;

    bf16x8 sk0, sk1, sv0, sv1;   // set A
    bf16x8 tk0, tk1, tv0, tv1;   // set B

#define KV_ISSUE(S0,S1,S2,S3,jj) { \
    size_t kb_ = ((size_t)b * 2048 + (jj) * 64 + srow) * 64 + scg * 8; \
    S0 = *reinterpret_cast<const bf16x8*>(&kbuf[kb_]); \
    S1 = *reinterpret_cast<const bf16x8*>(&kbuf[kb_ + (size_t)32 * 64]); \
    size_t vb_ = (size_t)b * 64 * 2048 + (size_t)srow * 2048 + (jj) * 64 + scg * 8; \
    S2 = *reinterpret_cast<const bf16x8*>(&vtbuf[vb_]); \
    S3 = *reinterpret_cast<const bf16x8*>(&vtbuf[vb_ + (size_t)32 * 2048]); }

#define KV_COMMIT(S0,S1,S2,S3,bi) { \
    *reinterpret_cast<bf16x8*>(&Klds[bi][srow * LDP + scg * 8]) = S0; \
    *reinterpret_cast<bf16x8*>(&Klds[bi][(32 + srow) * LDP + scg * 8]) = S1; \
    *reinterpret_cast<bf16x8*>(&Vlds[bi][srow * LDP + scg * 8]) = S2; \
    *reinterpret_cast<bf16x8*>(&Vlds[bi][(32 + srow) * LDP + scg * 8]) = S3; }

    const int nt = jend - jbeg;
    KV_ISSUE(sk0, sk1, sv0, sv1, jbeg);
    KV_COMMIT(sk0, sk1, sv0, sv1, 0);
    if (nt > 1) KV_ISSUE(tk0, tk1, tv0, tv1, jbeg + 1);
    BAR();

    for (int t = 0; t < nt; t++) {
        const int cur = t & 1;
        const int j = jbeg + t;
        // issue tile t+2 into the set freed by last iteration's commit
        if (t + 2 < nt) {
            if (cur) { KV_ISSUE(tk0, tk1, tv0, tv1, j + 2); }
            else     { KV_ISSUE(sk0, sk1, sv0, sv1, j + 2); }
        }
        const __bf16* KL = Klds[cur];
        const __bf16* VL = Vlds[cur];

        // S = Q K^T  (16 q x 64 kv per wave)
        f32x4 s[4];
        #pragma unroll
        for (int jf = 0; jf < 4; jf++) {
            f32x4 tacc = (f32x4){0.f, 0.f, 0.f, 0.f};
            #pragma unroll
            for (int kk = 0; kk < 2; kk++) {
                bf16x8 bk = *reinterpret_cast<const bf16x8*>(&KL[(jf * 16 + cl) * LDP + kk * 32 + e0]);
                tacc = __builtin_amdgcn_mfma_f32_16x16x32_bf16(aq[kk], bk, tacc, 0, 0, 0);
            }
            s[jf] = tacc;
        }

        // scale + causal & padding (column) mask; per-row tile max
        float tmax[4] = {-INFINITY, -INFINITY, -INFINITY, -INFINITY};
        #pragma unroll
        for (int jf = 0; jf < 4; jf++) {
            int kv = j * 64 + jf * 16 + cl;
            int mk = mask[b * 2048 + kv];
            #pragma unroll
            for (int r = 0; r < 4; r++) {
                float sv = s[jf][r] * 0.125f;
                bool ok = (mk != 0) && (kv <= qbase + r0 + r);
                sv = ok ? sv : -INFINITY;
                s[jf][r] = sv;
                tmax[r] = fmaxf(tmax[r], sv);
            }
        }

        // online softmax
        #pragma unroll
        for (int r = 0; r < 4; r++) {
            #pragma unroll
            for (int off = 1; off < 16; off <<= 1)
                tmax[r] = fmaxf(tmax[r], __shfl_xor(tmax[r], off));
            float mn = fmaxf(ms[r], tmax[r]);
            float alpha = (mn == -INFINITY) ? 1.0f : __expf(ms[r] - mn);
            float rs = 0.f;
            #pragma unroll
            for (int jf = 0; jf < 4; jf++) {
                float p = (mn == -INFINITY) ? 0.f : __expf(s[jf][r] - mn);
                s[jf][r] = p;
                rs += p;
            }
            #pragma unroll
            for (int off = 1; off < 16; off <<= 1)
                rs += __shfl_xor(rs, off);
            ls[r] = ls[r] * alpha + rs;
            ms[r] = mn;
            #pragma unroll
            for (int hf = 0; hf < 4; hf++) acc[hf][r] *= alpha;
        }

        // P -> wave-private LDS, then O += P V  (same-wave write->read: compiler lgkmcnt)
        #pragma unroll
        for (int jf = 0; jf < 4; jf++)
            #pragma unroll
            for (int r = 0; r < 4; r++)
                Plds[w][(r0 + r) * LDP + jf * 16 + cl] = (__bf16)s[jf][r];
        #pragma unroll
        for (int kk = 0; kk < 2; kk++) {
            bf16x8 ap = *reinterpret_cast<const bf16x8*>(&Plds[w][cl * LDP + kk * 32 + e0]);
            #pragma unroll
            for (int hf = 0; hf < 4; hf++) {
                bf16x8 bv = *reinterpret_cast<const bf16x8*>(&VL[(hf * 16 + cl) * LDP + kk * 32 + e0]);
                acc[hf] = __builtin_amdgcn_mfma_f32_16x16x32_bf16(ap, bv, acc[hf], 0, 0, 0);
            }
        }

        if (t + 1 < nt) {
            // commit tile t+1 (older outstanding set -> counted vmcnt), then raw barrier
            if (cur) { KV_COMMIT(sk0, sk1, sv0, sv1, cur ^ 1); }
            else     { KV_COMMIT(tk0, tk1, tv0, tv1, cur ^ 1); }
            BAR();
        }
    }
#undef KV_ISSUE
#undef KV_COMMIT

    if (nsplit == 1) {
        #pragma unroll
        for (int hf = 0; hf < 4; hf++)
            #pragma unroll
            for (int r = 0; r < 4; r++) {
                int qrow = qbase + r0 + r;
                int mq = mask[b * 2048 + qrow];
                float l = ls[r];
                float v = (l > 0.f && mq != 0) ? acc[hf][r] / l : 0.f;
                out[((size_t)b * 2048 + qrow) * 64 + hf * 16 + cl] = v;
            }
    } else {
        #pragma unroll
        for (int hf = 0; hf < 4; hf++)
            #pragma unroll
            for (int r = 0; r < 4; r++) {
                int qrow = qbase + r0 + r;
                accpart[((size_t)(b * nsplit + sp) * 2048 + qrow) * 64 + hf * 16 + cl] = acc[hf][r];
            }
        if (cl == 0) {
            #pragma unroll
            for (int r = 0; r < 4; r++) {
                int qrow = qbase + r0 + r;
                mlpart[((size_t)(b * nsplit + sp) * 2048 + qrow) * 2 + 0] = ms[r];
                mlpart[((size_t)(b * nsplit + sp) * 2048 + qrow) * 2 + 1] = ls[r];
            }
        }
    }
}

// ---------------- Kernel 3: combine split partials ----------------
template<int NS>
__global__ __launch_bounds__(256) void combine_kernel(
    const float* __restrict__ accpart, const float* __restrict__ mlpart,
    const int* __restrict__ mask, float* __restrict__ out)
{
    int idx = blockIdx.x * 256 + threadIdx.x;
    int qglob = idx >> 6;
    int h = idx & 63;
    int b = qglob >> 11;
    int qrow = qglob & 2047;

    if (mask[qglob] == 0) { out[idx] = 0.f; return; }

    float m_s[NS], l_s[NS];
    float M = -INFINITY;
    #pragma unroll
    for (int s = 0; s < NS; s++) {
        size_t mo = ((size_t)(b * NS + s) * 2048 + qrow) * 2;
        m_s[s] = mlpart[mo];
        l_s[s] = mlpart[mo + 1];
        M = fmaxf(M, m_s[s]);
    }
    if (M == -INFINITY) { out[idx] = 0.f; return; }

    float L = 0.f, O = 0.f;
    #pragma unroll
    for (int s = 0; s < NS; s++) {
        float wgt = (m_s[s] == -INFINITY) ? 0.f : __expf(m_s[s] - M);
        L += l_s[s] * wgt;
        O += wgt * accpart[((size_t)(b * NS + s) * 2048 + qrow) * 64 + h];
    }
    out[idx] = (L > 0.f) ? O / L : 0.f;
}

extern "C" void kernel_launch(void* const* d_in, const int* in_sizes, int n_in,
                              void* d_out, int out_size, void* d_ws, size_t ws_size,
                              hipStream_t stream) {
    const float* x  = (const float*)d_in[0];
    const float* Wk = (const float*)d_in[1];
    const float* Wq = (const float*)d_in[2];
    const float* Wv = (const float*)d_in[3];
    const int* mask = (const int*)d_in[4];
    float* out = (float*)d_out;

    const size_t NTOK = 8 * 2048;
    __bf16* kbuf  = (__bf16*)d_ws;                    // [16384][64]
    __bf16* qbuf  = kbuf + NTOK * 64;                 // [16384][64]
    __bf16* vtbuf = qbuf + NTOK * 64;                 // [8][64][2048]
    __bf16* wbf   = vtbuf + (size_t)8 * 64 * 2048;    // [192][1024]
    const size_t base_bytes = NTOK * 64 * 2 * 2 + (size_t)8 * 64 * 2048 * 2
                            + (size_t)192 * 1024 * 2;

    const size_t acc_per_split = NTOK * 64 * 4;
    const size_t ml_per_split  = NTOK * 2 * 4;
    int nsplit = 1;
    if (ws_size >= base_bytes + 4 * (acc_per_split + ml_per_split))      nsplit = 4;
    else if (ws_size >= base_bytes + 2 * (acc_per_split + ml_per_split)) nsplit = 2;

    float* accpart = (float*)((char*)d_ws + base_bytes);
    float* mlpart  = accpart + NTOK * 64 * nsplit;

    wconv_kernel<<<192, 256, 0, stream>>>(Wk, Wq, Wv, wbf);
    proj_kernel<<<256, 1024, 0, stream>>>(x, wbf, kbuf, qbuf, vtbuf);
    attn_kernel<<<dim3(32, nsplit, 8), 256, 0, stream>>>(
        qbuf, kbuf, vtbuf, mask, out, accpart, mlpart, nsplit, 32 / nsplit);
    if (nsplit == 4)
        combine_kernel<4><<<(16384 * 64) / 256, 256, 0, stream>>>(accpart, mlpart, mask, out);
    else if (nsplit == 2)
        combine_kernel<2><<<(16384 * 64) / 256, 256, 0, stream>>>(accpart, mlpart, mask, out);
}

// Round 7
// 60.871 us; speedup vs baseline: 1.2034x; 1.2034x over previous
//
#include <hip/hip_runtime.h>
#include <hip/hip_bf16.h>

typedef __bf16 bf16x8 __attribute__((ext_vector_type(8)));
typedef __bf16 bf16x4 __attribute__((ext_vector_type(4)));
typedef float  f32x4  __attribute__((ext_vector_type(4)));

#define LDP 72  // padded LDS row stride in bf16 elems (144B)

// Raw barrier: drain DS only. In-flight global prefetch loads survive (no vmcnt drain).
#define BAR() { asm volatile("s_waitcnt lgkmcnt(0)" ::: "memory"); __builtin_amdgcn_s_barrier(); }

// ---------------- Kernel 0a: W -> bf16 pre-conversion ----------------
__global__ __launch_bounds__(256) void wconv_kernel(
    const float* __restrict__ Wk, const float* __restrict__ Wq,
    const float* __restrict__ Wv, __bf16* __restrict__ wbf)
{
    int idx = blockIdx.x * 256 + threadIdx.x;      // 0 .. 49151
    int row = idx >> 8;
    int c4  = idx & 255;
    const float* wp = (row < 64) ? Wk + (size_t)row * 1024
                    : (row < 128) ? Wq + (size_t)(row - 64) * 1024
                                  : Wv + (size_t)(row - 128) * 1024;
    float4 f = *reinterpret_cast<const float4*>(wp + c4 * 4);
    bf16x4 v; v[0] = (__bf16)f.x; v[1] = (__bf16)f.y; v[2] = (__bf16)f.z; v[3] = (__bf16)f.w;
    *reinterpret_cast<bf16x4*>(&wbf[(size_t)row * 1024 + c4 * 4]) = v;
}

// ---------------- Kernel 0b: pack attention_mask into bitwords ----------------
// maskw[b*64 + w]: bit i = (mask[b*2048 + w*32 + i] != 0). 512 words total.
__global__ __launch_bounds__(512) void maskpack_kernel(
    const int* __restrict__ mask, unsigned* __restrict__ maskw)
{
    int wdx = threadIdx.x;   // 0..511 (one block)
    unsigned wv = 0;
    #pragma unroll
    for (int bit = 0; bit < 32; bit++)
        wv |= (mask[wdx * 32 + bit] != 0 ? 1u : 0u) << bit;
    maskw[wdx] = wv;
}

// ---------------- Kernel 1: fused QKV projection GEMM (depth-2 pipeline) ----------------
__global__ __launch_bounds__(1024) void proj_kernel(
    const float* __restrict__ x, const __bf16* __restrict__ wbf,
    __bf16* __restrict__ kbuf, __bf16* __restrict__ qbuf, __bf16* __restrict__ vtbuf)
{
    __shared__ __align__(16) __bf16 Slds[2][256 * LDP];
    __shared__ __align__(16) __bf16 Vtl[64 * LDP];

    const int tid  = threadIdx.x;
    const int lane = tid & 63;
    const int wid  = tid >> 6;     // 0..15
    const int wm   = wid >> 2;     // 0..3 : 16-row group
    const int wn   = wid & 3;      // 0..3 : 48-col group
    const int mbase = blockIdx.x * 64;

    const int cl = lane & 15;
    const int e0 = (lane >> 4) * 8;
    const int r0 = (lane >> 4) * 4;

    const int arow = tid >> 4, acg = tid & 15;
    const float* aptr = x + (size_t)(mbase + arow) * 1024 + acg * 4;

    float4 a0, a1;
    bf16x4 w0[3], w1[3];

#define ISSUE(aset, wset, kb) { \
    aset = *reinterpret_cast<const float4*>(aptr + (kb)); \
    _Pragma("unroll") \
    for (int i_ = 0; i_ < 3; i_++) { \
        int c_ = i_ * 1024 + tid; \
        wset[i_] = *reinterpret_cast<const bf16x4*>(&wbf[(size_t)(c_ >> 4) * 1024 + (kb) + (c_ & 15) * 4]); \
    } }

#define COMMIT(aset, wset, bufi) { \
    bf16x4 av_; \
    av_[0] = (__bf16)aset.x; av_[1] = (__bf16)aset.y; av_[2] = (__bf16)aset.z; av_[3] = (__bf16)aset.w; \
    *reinterpret_cast<bf16x4*>(&Slds[bufi][arow * LDP + acg * 4]) = av_; \
    _Pragma("unroll") \
    for (int i_ = 0; i_ < 3; i_++) { \
        int c_ = i_ * 1024 + tid; \
        *reinterpret_cast<bf16x4*>(&Slds[bufi][(64 + (c_ >> 4)) * LDP + (c_ & 15) * 4]) = wset[i_]; \
    } }

    f32x4 acc[3];
    #pragma unroll
    for (int n = 0; n < 3; n++) acc[n] = (f32x4){0.f, 0.f, 0.f, 0.f};

    ISSUE(a0, w0, 0);
    COMMIT(a0, w0, 0);
    ISSUE(a1, w1, 64);
    BAR();

    #pragma unroll 2
    for (int j = 0; j < 16; j++) {
        if (j < 14) {
            if (j & 1) { ISSUE(a1, w1, (j + 2) * 64); }
            else       { ISSUE(a0, w0, (j + 2) * 64); }
        }
        const __bf16* buf = Slds[j & 1];
        #pragma unroll
        for (int kk = 0; kk < 2; kk++) {
            bf16x8 a = *reinterpret_cast<const bf16x8*>(&buf[(wm * 16 + cl) * LDP + kk * 32 + e0]);
            #pragma unroll
            for (int nf = 0; nf < 3; nf++) {
                bf16x8 b = *reinterpret_cast<const bf16x8*>(&buf[(64 + wn * 48 + nf * 16 + cl) * LDP + kk * 32 + e0]);
                acc[nf] = __builtin_amdgcn_mfma_f32_16x16x32_bf16(a, b, acc[nf], 0, 0, 0);
            }
        }
        if (j < 15) {
            if (j & 1) { COMMIT(a0, w0, 0); }
            else       { COMMIT(a1, w1, 1); }
            BAR();
        }
    }
#undef ISSUE
#undef COMMIT

    #pragma unroll
    for (int nf = 0; nf < 3; nf++) {
        int c = wn * 48 + nf * 16 + cl;
        #pragma unroll
        for (int r = 0; r < 4; r++) {
            int mrel = wm * 16 + r0 + r;
            float v = acc[nf][r];
            if (c < 64)        kbuf[(size_t)(mbase + mrel) * 64 + c]         = (__bf16)v;
            else if (c < 128)  qbuf[(size_t)(mbase + mrel) * 64 + (c - 64)]  = (__bf16)v;
            else               Vtl[(c - 128) * LDP + mrel]                   = (__bf16)v;
        }
    }
    __syncthreads();
    {
        int b   = mbase >> 11;
        int tof = mbase & 2047;
        int h   = tid >> 4;
        int seg = tid & 15;
        bf16x4 v4 = *reinterpret_cast<const bf16x4*>(&Vtl[h * LDP + seg * 4]);
        *reinterpret_cast<bf16x4*>(&vtbuf[(size_t)b * 64 * 2048 + (size_t)h * 2048 + tof + seg * 4]) = v4;
    }
}

// ---------------- Kernel 2: flash attention, swapped-QK, split KV ----------------
// grid (32 q-tiles, nsplit, 8 batches), 256 threads = 4 waves; wave w owns 16 q rows.
// QK^T computed as mfma(K_frag, Q_frag) -> S^T fragments: lane holds S[kv][q] for
// ONE q (= qbase + (lane&15)) and 16 kv values -> softmax is 15 in-reg ops + 2
// shuffles. Column mask via packed bitwords (no loads on critical path). Single
// LDS buffer (27.6KB -> 5 blocks/CU) + register prefetch + raw barriers.
__global__ __launch_bounds__(256) void attn_kernel(
    const __bf16* __restrict__ qbuf, const __bf16* __restrict__ kbuf,
    const __bf16* __restrict__ vtbuf, const unsigned* __restrict__ maskw,
    const int* __restrict__ mask,
    float* __restrict__ out, float* __restrict__ accpart, float* __restrict__ mlpart,
    int nsplit, int tps)
{
    __shared__ __align__(16) __bf16 Klds[64 * LDP];
    __shared__ __align__(16) __bf16 Vlds[64 * LDP];
    __shared__ __align__(16) __bf16 Plds[4][16 * LDP];

    const int tid  = threadIdx.x;
    const int lane = tid & 63;
    const int w    = tid >> 6;
    const int qt   = blockIdx.x;
    const int sp   = blockIdx.y;
    const int b    = blockIdx.z;
    const int qbase = qt * 64 + w * 16;

    const int jbeg = sp * tps;
    const int jend = min((sp + 1) * tps, qt + 1);

    if (nsplit > 1 && jbeg >= jend) {
        float* ap = accpart + ((size_t)(b * nsplit + sp) * 2048 + qt * 64) * 64;
        for (int i = tid; i < 64 * 64; i += 256) ap[i] = 0.f;
        float* mp = mlpart + ((size_t)(b * nsplit + sp) * 2048 + qt * 64) * 2;
        for (int i = tid; i < 64; i += 256) { mp[2 * i] = -INFINITY; mp[2 * i + 1] = 0.f; }
        return;
    }

    const int cl = lane & 15;
    const int e0 = (lane >> 4) * 8;
    const int r0 = (lane >> 4) * 4;
    const int qs = qbase + cl;          // the q-row this lane owns in S^T layout

    bf16x8 aq[2];
    #pragma unroll
    for (int kk = 0; kk < 2; kk++)
        aq[kk] = *reinterpret_cast<const bf16x8*>(&qbuf[((size_t)b * 2048 + qs) * 64 + kk * 32 + e0]);

    float m = -INFINITY, l = 0.f;       // softmax state for q = qs (replicated on 4 lanes)
    f32x4 acc[4];                       // acc[hf][r] = O[qbase + r0 + r][hf*16 + cl]
    #pragma unroll
    for (int hf = 0; hf < 4; hf++) acc[hf] = (f32x4){0.f, 0.f, 0.f, 0.f};

    const int srow = tid >> 3;   // 0..31
    const int scg  = tid & 7;

    bf16x8 k0, k1, v0, v1;       // prefetch registers

#define KV_ISSUE(jj) { \
    size_t kb_ = ((size_t)b * 2048 + (jj) * 64 + srow) * 64 + scg * 8; \
    k0 = *reinterpret_cast<const bf16x8*>(&kbuf[kb_]); \
    k1 = *reinterpret_cast<const bf16x8*>(&kbuf[kb_ + (size_t)32 * 64]); \
    size_t vb_ = (size_t)b * 64 * 2048 + (size_t)srow * 2048 + (jj) * 64 + scg * 8; \
    v0 = *reinterpret_cast<const bf16x8*>(&vtbuf[vb_]); \
    v1 = *reinterpret_cast<const bf16x8*>(&vtbuf[vb_ + (size_t)32 * 2048]); }

#define KV_COMMIT() { \
    *reinterpret_cast<bf16x8*>(&Klds[srow * LDP + scg * 8]) = k0; \
    *reinterpret_cast<bf16x8*>(&Klds[(32 + srow) * LDP + scg * 8]) = k1; \
    *reinterpret_cast<bf16x8*>(&Vlds[srow * LDP + scg * 8]) = v0; \
    *reinterpret_cast<bf16x8*>(&Vlds[(32 + srow) * LDP + scg * 8]) = v1; }

    const int nt = jend - jbeg;
    KV_ISSUE(jbeg);
    KV_COMMIT();
    BAR();

    for (int t = 0; t < nt; t++) {
        const int j = jbeg + t;
        if (t + 1 < nt) KV_ISSUE(j + 1);   // in flight during compute + BAR

        // S^T = (K Q^T): s[jf][r] = S[kv = jf*16 + r0 + r][q = qs]
        f32x4 s[4];
        #pragma unroll
        for (int jf = 0; jf < 4; jf++) {
            f32x4 tacc = (f32x4){0.f, 0.f, 0.f, 0.f};
            #pragma unroll
            for (int kk = 0; kk < 2; kk++) {
                bf16x8 bk = *reinterpret_cast<const bf16x8*>(&Klds[(jf * 16 + cl) * LDP + kk * 32 + e0]);
                tacc = __builtin_amdgcn_mfma_f32_16x16x32_bf16(bk, aq[kk], tacc, 0, 0, 0);
            }
            s[jf] = tacc;
        }

        // scale + causal & column mask (bitword) + in-lane tile max over 16 kv
        const unsigned mw0 = maskw[b * 64 + j * 2];
        const unsigned mw1 = maskw[b * 64 + j * 2 + 1];
        float tmax = -INFINITY;
        #pragma unroll
        for (int jf = 0; jf < 4; jf++) {
            unsigned mw = (jf < 2) ? mw0 : mw1;
            #pragma unroll
            for (int r = 0; r < 4; r++) {
                int kvl = jf * 16 + r0 + r;              // 0..63 within tile
                bool ok = ((mw >> (kvl & 31)) & 1u) && (j * 64 + kvl <= qs);
                float sv = s[jf][r] * 0.125f;
                sv = ok ? sv : -INFINITY;
                s[jf][r] = sv;
                tmax = fmaxf(tmax, sv);
            }
        }
        // reduce across the 4 lanes sharing q=qs (lanes cl, cl+16, cl+32, cl+48)
        tmax = fmaxf(tmax, __shfl_xor(tmax, 16));
        tmax = fmaxf(tmax, __shfl_xor(tmax, 32));

        float mn = fmaxf(m, tmax);
        float alpha = (mn == -INFINITY) ? 1.0f : __expf(m - mn);
        float rs = 0.f;
        #pragma unroll
        for (int jf = 0; jf < 4; jf++)
            #pragma unroll
            for (int r = 0; r < 4; r++) {
                float p = (mn == -INFINITY) ? 0.f : __expf(s[jf][r] - mn);
                s[jf][r] = p;
                rs += p;
            }
        rs += __shfl_xor(rs, 16);
        rs += __shfl_xor(rs, 32);
        l = l * alpha + rs;
        m = mn;

        // broadcast alpha to the acc layout (lane needs alpha of q = qbase + r0 + r,
        // which lives at lane r0+r) and rescale O
        #pragma unroll
        for (int r = 0; r < 4; r++) {
            float ar = __shfl(alpha, r0 + r);
            #pragma unroll
            for (int hf = 0; hf < 4; hf++) acc[hf][r] *= ar;
        }

        // P^T -> wave-private LDS: Plds[q][kv]; lane writes 4x bf16x4 (column q = cl)
        #pragma unroll
        for (int jf = 0; jf < 4; jf++) {
            bf16x4 p4;
            #pragma unroll
            for (int r = 0; r < 4; r++) p4[r] = (__bf16)s[jf][r];
            *reinterpret_cast<bf16x4*>(&Plds[w][cl * LDP + jf * 16 + r0]) = p4;
        }
        // O += P V   (A = P^T rows from Plds, B = Vt rows; same-wave lgkmcnt dep)
        #pragma unroll
        for (int kk = 0; kk < 2; kk++) {
            bf16x8 ap = *reinterpret_cast<const bf16x8*>(&Plds[w][cl * LDP + kk * 32 + e0]);
            #pragma unroll
            for (int hf = 0; hf < 4; hf++) {
                bf16x8 bv = *reinterpret_cast<const bf16x8*>(&Vlds[(hf * 16 + cl) * LDP + kk * 32 + e0]);
                acc[hf] = __builtin_amdgcn_mfma_f32_16x16x32_bf16(ap, bv, acc[hf], 0, 0, 0);
            }
        }

        BAR();                               // all waves done reading K/V
        if (t + 1 < nt) {
            KV_COMMIT();                     // overwrite with next tile (loads landed)
            BAR();                           // writes visible before next compute
        }
    }
#undef KV_ISSUE
#undef KV_COMMIT

    if (nsplit == 1) {
        #pragma unroll
        for (int r = 0; r < 4; r++) {
            int qrow = qbase + r0 + r;
            float lq = __shfl(l, r0 + r);
            int mq = mask[b * 2048 + qrow];
            #pragma unroll
            for (int hf = 0; hf < 4; hf++) {
                float v = (lq > 0.f && mq != 0) ? acc[hf][r] / lq : 0.f;
                out[((size_t)b * 2048 + qrow) * 64 + hf * 16 + cl] = v;
            }
        }
    } else {
        #pragma unroll
        for (int hf = 0; hf < 4; hf++)
            #pragma unroll
            for (int r = 0; r < 4; r++) {
                int qrow = qbase + r0 + r;
                accpart[((size_t)(b * nsplit + sp) * 2048 + qrow) * 64 + hf * 16 + cl] = acc[hf][r];
            }
        if (lane < 16) {                     // lane cl holds (m,l) for q = qbase + cl
            int qrow = qbase + lane;
            mlpart[((size_t)(b * nsplit + sp) * 2048 + qrow) * 2 + 0] = m;
            mlpart[((size_t)(b * nsplit + sp) * 2048 + qrow) * 2 + 1] = l;
        }
    }
}

// ---------------- Kernel 3: combine split partials ----------------
template<int NS>
__global__ __launch_bounds__(256) void combine_kernel(
    const float* __restrict__ accpart, const float* __restrict__ mlpart,
    const int* __restrict__ mask, float* __restrict__ out)
{
    int idx = blockIdx.x * 256 + threadIdx.x;
    int qglob = idx >> 6;
    int h = idx & 63;
    int b = qglob >> 11;
    int qrow = qglob & 2047;

    if (mask[qglob] == 0) { out[idx] = 0.f; return; }

    float m_s[NS], l_s[NS];
    float M = -INFINITY;
    #pragma unroll
    for (int s = 0; s < NS; s++) {
        size_t mo = ((size_t)(b * NS + s) * 2048 + qrow) * 2;
        m_s[s] = mlpart[mo];
        l_s[s] = mlpart[mo + 1];
        M = fmaxf(M, m_s[s]);
    }
    if (M == -INFINITY) { out[idx] = 0.f; return; }

    float L = 0.f, O = 0.f;
    #pragma unroll
    for (int s = 0; s < NS; s++) {
        float wgt = (m_s[s] == -INFINITY) ? 0.f : __expf(m_s[s] - M);
        L += l_s[s] * wgt;
        O += wgt * accpart[((size_t)(b * NS + s) * 2048 + qrow) * 64 + h];
    }
    out[idx] = (L > 0.f) ? O / L : 0.f;
}

extern "C" void kernel_launch(void* const* d_in, const int* in_sizes, int n_in,
                              void* d_out, int out_size, void* d_ws, size_t ws_size,
                              hipStream_t stream) {
    const float* x  = (const float*)d_in[0];
    const float* Wk = (const float*)d_in[1];
    const float* Wq = (const float*)d_in[2];
    const float* Wv = (const float*)d_in[3];
    const int* mask = (const int*)d_in[4];
    float* out = (float*)d_out;

    const size_t NTOK = 8 * 2048;
    __bf16* kbuf  = (__bf16*)d_ws;                    // [16384][64]
    __bf16* qbuf  = kbuf + NTOK * 64;                 // [16384][64]
    __bf16* vtbuf = qbuf + NTOK * 64;                 // [8][64][2048]
    __bf16* wbf   = vtbuf + (size_t)8 * 64 * 2048;    // [192][1024]
    unsigned* maskw = (unsigned*)(wbf + (size_t)192 * 1024);   // [512]
    const size_t base_bytes = NTOK * 64 * 2 * 2 + (size_t)8 * 64 * 2048 * 2
                            + (size_t)192 * 1024 * 2 + 512 * 4;

    const size_t acc_per_split = NTOK * 64 * 4;
    const size_t ml_per_split  = NTOK * 2 * 4;
    int nsplit = 1;
    if (ws_size >= base_bytes + 4 * (acc_per_split + ml_per_split))      nsplit = 4;
    else if (ws_size >= base_bytes + 2 * (acc_per_split + ml_per_split)) nsplit = 2;

    float* accpart = (float*)((char*)d_ws + base_bytes);
    float* mlpart  = accpart + NTOK * 64 * nsplit;

    wconv_kernel<<<192, 256, 0, stream>>>(Wk, Wq, Wv, wbf);
    maskpack_kernel<<<1, 512, 0, stream>>>(mask, maskw);
    proj_kernel<<<256, 1024, 0, stream>>>(x, wbf, kbuf, qbuf, vtbuf);
    attn_kernel<<<dim3(32, nsplit, 8), 256, 0, stream>>>(
        qbuf, kbuf, vtbuf, maskw, mask, out, accpart, mlpart, nsplit, 32 / nsplit);
    if (nsplit == 4)
        combine_kernel<4><<<(16384 * 64) / 256, 256, 0, stream>>>(accpart, mlpart, mask, out);
    else if (nsplit == 2)
        combine_kernel<2><<<(16384 * 64) / 256, 256, 0, stream>>>(accpart, mlpart, mask, out);
}